// Round 12
// baseline (1248.814 us; speedup 1.0000x reference)
//
#include <hip/hip_runtime.h>
#include <hip/hip_bf16.h>

constexpr int DV     = 200;
constexpr int N_ENT  = 14541;
constexpr int N_EDGE = 544230;
constexpr int HALF_E = N_EDGE / 2;
constexpr int NSEG   = 2 * N_ENT;
constexpr int BB     = 2048;
constexpr int NF     = 96;
constexpr int FLATN  = 38400;
constexpr float LEAK = 0.2f;
constexpr float BEPS = 1e-5f;

typedef unsigned int u32;
typedef unsigned short u16;
typedef __attribute__((ext_vector_type(8))) short bf16x8;
typedef __attribute__((ext_vector_type(4))) float f32x4;
typedef __attribute__((ext_vector_type(4))) unsigned short u16x4;

// ---------------- workspace layout (in 4-byte words) ----------------
constexpr size_t OFF_S    = 0;                       // 544230 edge scores
constexpr size_t OFF_EID  = 544230;                  // 544230 CSR edge ids
constexpr size_t OFF_CNT  = 1088460;                 // 29082 u32 counts/fill-ptrs (zeroed)
constexpr size_t OFF_OFFS = 1117542;                 // 29082 u32 seg offsets
constexpr size_t OFF_AGG  = 1146624;                 // 2*14541*200 (zeroed)
constexpr size_t OFF_FC   = 6963218;                 // 2048*200 (zeroed)
constexpr size_t ZERO_BEG = OFF_CNT;
constexpr size_t ZERO_END = OFF_FC + 409600;         // 7372818
constexpr size_t OFF_V    = 7372818;                 // 400 (v_in|v_out)
// --- reused (dead) regions ---
constexpr size_t OFF_WTH  = 0;                        // 200*38400 bf16 = 3,840,000 w
constexpr size_t OFF_ENTH = 3840000;                  // 14541*208 bf16 = 1,512,264 w
constexpr size_t OFF_ENTL = 5352264;                  // 1,512,264 w (end 6,864,528)
constexpr size_t OFF_WTL  = 7373220;                  // 3,840,000 w (end 11,213,220) 16B-aligned
constexpr size_t OFF_EMB  = 7373218;                  // 14541*200 embed*loop
constexpr size_t OFF_EPRE = 10281418;                 // 14541*200 ent pre-bn
constexpr size_t OFF_ENT  = 13189618;                 // 14541*200 ent final (f32)
constexpr size_t OFF_RELO = 16097818;                 // 474*200 rel_out
constexpr size_t OFF_CM   = 16192618;                 // 200 col means
constexpr size_t OFF_CV   = 16192818;                 // 200 col vars
constexpr size_t OFF_CHEQ = 16193018;                 // 2048*400 (dead after conv)
constexpr size_t OFF_YH   = 16193020;                 // 2048*208 bf16 (aliases cheq)
constexpr size_t OFF_YL   = 16406012;                 // 212,992 w (end 16,619,004)
constexpr size_t OFF_P0   = 17012218;                 // 4096 bn0 partials
constexpr size_t OFF_ST0  = 17016314;                 // 2 bn0 stats
constexpr size_t OFF_CHP  = 17016316;                 // 2048*192 bn1 partials
constexpr size_t OFF_B1SC = 17409532;                 // 96
constexpr size_t OFF_B1BI = 17409628;                 // 96
constexpr size_t OFF_XC   = 17819324;                 // bf16 conv out: 39321600 words
constexpr size_t WS_WORDS = OFF_XC + 39321600;

__device__ inline float bf2f(u16 u) { return __uint_as_float(((u32)u) << 16); }
__device__ inline u16 f2bf(float f) {
    __hip_bfloat16 h = __float2bfloat16(f);
    return *reinterpret_cast<u16*>(&h);
}
// async global->LDS 16B (dest = wave-uniform base + lane*16; source per-lane)
__device__ inline void gl_lds16(const void* g, void* l) {
    __builtin_amdgcn_global_load_lds(
        (const __attribute__((address_space(1))) void*)g,
        (__attribute__((address_space(3))) void*)l, 16, 0, 0);
}

// ---------------- tiny: v = W @ att for both directions ----------------
__global__ void k_vatt(const float* __restrict__ w_in, const float* __restrict__ w_out,
                       const float* __restrict__ att_in, const float* __restrict__ att_out,
                       float* __restrict__ v) {
    int t = blockIdx.x * 256 + threadIdx.x;
    if (t < DV) {
        float s = 0.f;
        for (int j = 0; j < DV; ++j) s += w_in[t * DV + j] * att_in[j];
        v[t] = s;
    } else if (t < 2 * DV) {
        int k = t - DV;
        float s = 0.f;
        for (int j = 0; j < DV; ++j) s += w_out[k * DV + j] * att_out[j];
        v[t] = s;
    }
}

// ---------------- edge pass A: score only (no atomics) ----------------
__global__ void k_edge_score(const float* __restrict__ embed, const float* __restrict__ rel,
                             const int* __restrict__ eidx, const int* __restrict__ etype,
                             const float* __restrict__ v, float* __restrict__ s_all) {
    int gw = (blockIdx.x * 256 + threadIdx.x) >> 6;
    int lane = threadIdx.x & 63;
    if (gw >= N_EDGE) return;
    int e = gw;
    int dst = eidx[N_EDGE + e], et = etype[e];
    int dir = (e >= HALF_E);
    const float* vv = v + dir * DV;
    const float* er = embed + (size_t)dst * DV;
    const float* rr = rel + (size_t)et * DV;
    float acc = 0.f;
    for (int d = lane; d < DV; d += 64) acc += er[d] * rr[d] * vv[d];
    for (int off = 32; off > 0; off >>= 1) acc += __shfl_down(acc, off);
    if (lane == 0) {
        float s = acc > 0.f ? acc : LEAK * acc;
        s_all[e] = s;
    }
}

// ---------------- CSR build: histogram ----------------
__global__ void k_hist(const int* __restrict__ eidx, u32* __restrict__ cnt) {
    int e = blockIdx.x * 256 + threadIdx.x;
    if (e >= N_EDGE) return;
    int seg = (e >= HALF_E ? N_ENT : 0) + eidx[e];
    atomicAdd(&cnt[seg], 1u);
}

// ---------------- CSR build: single-block exclusive scan ----------------
__global__ void k_scan(u32* __restrict__ cnt, u32* __restrict__ offs) {
    __shared__ u32 s[256];
    __shared__ u32 base;
    if (threadIdx.x == 0) base = 0;
    __syncthreads();
    for (int c0 = 0; c0 < NSEG; c0 += 256) {
        int i = c0 + threadIdx.x;
        u32 vv = (i < NSEG) ? cnt[i] : 0;
        s[threadIdx.x] = vv;
        __syncthreads();
        for (int o = 1; o < 256; o <<= 1) {
            u32 t = (threadIdx.x >= (u32)o) ? s[threadIdx.x - o] : 0u;
            __syncthreads();
            s[threadIdx.x] += t;
            __syncthreads();
        }
        u32 exc = base + s[threadIdx.x] - vv;
        if (i < NSEG) { offs[i] = exc; cnt[i] = exc; }
        __syncthreads();
        if (threadIdx.x == 255) base += s[255];
        __syncthreads();
    }
}

// ---------------- CSR build: scatter edge ids ----------------
__global__ void k_scatter(const int* __restrict__ eidx, u32* __restrict__ pos,
                          u32* __restrict__ eid) {
    int e = blockIdx.x * 256 + threadIdx.x;
    if (e >= N_EDGE) return;
    int seg = (e >= HALF_E ? N_ENT : 0) + eidx[e];
    u32 slot = atomicAdd(&pos[seg], 1u);
    eid[slot] = (u32)e;
}

// ---------------- fused segment softmax + aggregation (1 wave / segment) ----------------
__global__ void k_seg_agg(const float* __restrict__ embed, const float* __restrict__ rel,
                          const int* __restrict__ eidx, const int* __restrict__ etype,
                          const float* __restrict__ s_all, const u32* __restrict__ offs,
                          const u32* __restrict__ eid, float* __restrict__ aggC) {
    int gw = (blockIdx.x * 256 + threadIdx.x) >> 6;
    int lane = threadIdx.x & 63;
    if (gw >= NSEG) return;
    u32 beg = offs[gw];
    u32 end = (gw == NSEG - 1) ? (u32)N_EDGE : offs[gw + 1];
    int deg = (int)(end - beg);
    if (deg == 0) return;
    float m = -1e30f;
    for (int i = lane; i < deg; i += 64) m = fmaxf(m, s_all[eid[beg + i]]);
    for (int o = 32; o > 0; o >>= 1) m = fmaxf(m, __shfl_xor(m, o));
    float dsum = 0.f;
    for (int i = lane; i < deg; i += 64) dsum += expf(s_all[eid[beg + i]] - m);
    for (int o = 32; o > 0; o >>= 1) dsum += __shfl_xor(dsum, o);
    float inv = 1.f / (dsum + 1e-16f);
    float a0 = 0.f, a1 = 0.f, a2 = 0.f, a3 = 0.f;
    bool t3 = (lane < 8);
    for (int j = 0; j < deg; ++j) {
        int e = (int)eid[beg + j];
        float alpha = expf(s_all[e] - m) * inv;
        int dst = eidx[N_EDGE + e], et = etype[e];
        const float* er = embed + (size_t)dst * DV;
        const float* rr = rel + (size_t)et * DV;
        float p0 = er[lane] * rr[lane];
        float p1 = er[lane + 64] * rr[lane + 64];
        float p2 = er[lane + 128] * rr[lane + 128];
        float p3 = t3 ? er[lane + 192] * rr[lane + 192] : 0.f;
        a0 = fmaf(p0, alpha, a0);
        a1 = fmaf(p1, alpha, a1);
        a2 = fmaf(p2, alpha, a2);
        a3 = fmaf(p3, alpha, a3);
    }
    float* ag = aggC + (size_t)gw * DV;
    ag[lane] = a0;
    ag[lane + 64] = a1;
    ag[lane + 128] = a2;
    if (t3) ag[lane + 192] = a3;
}

// ---------------- embed * loop_rel (broadcast) ----------------
__global__ void k_embloop(const float* __restrict__ embed, const float* __restrict__ lr,
                          float* __restrict__ outp) {
    size_t i = (size_t)blockIdx.x * 256 + threadIdx.x;
    if (i < (size_t)N_ENT * DV) outp[i] = embed[i] * lr[i % DV];
}

// ---------------- generic fp32 GEMM: C (+)= A[MxK] @ B[KxN] ----------------
__global__ void gemm_nn(const float* __restrict__ A, const float* __restrict__ B,
                        float* __restrict__ C, int M, int N, int K, int beta) {
    __shared__ float As[16][65];
    __shared__ float Bs[16][64];
    int bm = blockIdx.x * 64, bn = blockIdx.y * 64;
    int tx = threadIdx.x & 15, ty = threadIdx.x >> 4;
    float acc[4][4] = {};
    for (int k0 = 0; k0 < K; k0 += 16) {
        for (int i = threadIdx.x; i < 1024; i += 256) {
            int m = i >> 4, k = i & 15;
            int gm = bm + m, gk = k0 + k;
            As[k][m] = (gm < M && gk < K) ? A[(size_t)gm * K + gk] : 0.f;
        }
        for (int i = threadIdx.x; i < 1024; i += 256) {
            int k = i >> 6, n = i & 63;
            int gk = k0 + k, gn = bn + n;
            Bs[k][n] = (gk < K && gn < N) ? B[(size_t)gk * N + gn] : 0.f;
        }
        __syncthreads();
#pragma unroll
        for (int k = 0; k < 16; ++k) {
            float a[4], bv[4];
#pragma unroll
            for (int i = 0; i < 4; i++) a[i] = As[k][ty * 4 + i];
#pragma unroll
            for (int j = 0; j < 4; j++) bv[j] = Bs[k][tx * 4 + j];
#pragma unroll
            for (int i = 0; i < 4; i++)
#pragma unroll
                for (int j = 0; j < 4; j++) acc[i][j] += a[i] * bv[j];
        }
        __syncthreads();
    }
#pragma unroll
    for (int i = 0; i < 4; i++) {
        int r = bm + ty * 4 + i;
        if (r >= M) continue;
#pragma unroll
        for (int j = 0; j < 4; j++) {
            int c = bn + tx * 4 + j;
            if (c >= N) continue;
            size_t idx = (size_t)r * N + c;
            C[idx] = beta ? C[idx] + acc[i][j] : acc[i][j];
        }
    }
}

// ---------------- per-column stats over R x 200 ----------------
__global__ void k_colstats(const float* __restrict__ X, int R,
                           float* __restrict__ cm, float* __restrict__ cv) {
    int col = blockIdx.x;
    __shared__ float rs[256], rss[256];
    float s = 0.f, ss = 0.f;
    for (int r = threadIdx.x; r < R; r += 256) {
        float x = X[(size_t)r * DV + col];
        s += x; ss += x * x;
    }
    rs[threadIdx.x] = s; rss[threadIdx.x] = ss;
    __syncthreads();
    for (int o = 128; o > 0; o >>= 1) {
        if (threadIdx.x < o) { rs[threadIdx.x] += rs[threadIdx.x + o]; rss[threadIdx.x] += rss[threadIdx.x + o]; }
        __syncthreads();
    }
    if (threadIdx.x == 0) {
        float m = rs[0] / R;
        cm[col] = m;
        cv[col] = rss[0] / R - m * m;
    }
}

// ---------------- bn(ent): tanh + f32 + bf16 hi/lo (padded pitch 208) ----------------
__global__ void k_bn_ent(const float* __restrict__ epre, const float* __restrict__ cm,
                         const float* __restrict__ cv, const float* __restrict__ g,
                         const float* __restrict__ b, float* __restrict__ ent,
                         u16* __restrict__ eh, u16* __restrict__ el) {
    size_t i = (size_t)blockIdx.x * 256 + threadIdx.x;
    if (i >= (size_t)N_ENT * 208) return;
    int row = (int)(i / 208), col = (int)(i % 208);
    if (col < DV) {
        float val = (epre[(size_t)row * DV + col] - cm[col]) * rsqrtf(cv[col] + 9.f * BEPS) * g[col] + b[col];
        val = tanhf(val);
        ent[(size_t)row * DV + col] = val;
        u16 h = f2bf(val);
        eh[i] = h;
        el[i] = f2bf(val - bf2f(h));
    } else { eh[i] = 0; el[i] = 0; }
}

// ---------------- bn2(fc_out): relu + bf16 hi/lo Y (padded pitch 208) ----------------
__global__ void k_bn2y(const float* __restrict__ fc, const float* __restrict__ cm,
                       const float* __restrict__ cv, const float* __restrict__ g,
                       const float* __restrict__ b, u16* __restrict__ yh,
                       u16* __restrict__ yl) {
    size_t i = (size_t)blockIdx.x * 256 + threadIdx.x;
    if (i >= (size_t)BB * 208) return;
    int row = (int)(i / 208), col = (int)(i % 208);
    if (col < DV) {
        float val = (fc[(size_t)row * DV + col] - cm[col]) * rsqrtf(cv[col] + BEPS) * g[col] + b[col];
        val = fmaxf(val, 0.f);
        u16 h = f2bf(val);
        yh[i] = h;
        yl[i] = f2bf(val - bf2f(h));
    } else { yh[i] = 0; yl[i] = 0; }
}

// ---------------- fc_w transpose + hi/lo split: W[38400][200] -> Wt[200][38400] ----------------
__global__ __launch_bounds__(256) void k_wt(const float* __restrict__ W,
                                            u16* __restrict__ Wth, u16* __restrict__ Wtl) {
    __shared__ float lds[64][65];
    int k0 = blockIdx.x * 64, n0 = blockIdx.y * 64;
    for (int idx = threadIdx.x; idx < 4096; idx += 256) {
        int kl = idx >> 6, nl = idx & 63;
        int gk = k0 + kl, gn = n0 + nl;
        lds[kl][nl] = (gn < DV) ? W[(size_t)gk * DV + gn] : 0.f;
    }
    __syncthreads();
    int nl = threadIdx.x >> 2, kq = threadIdx.x & 3;
    int gn = n0 + nl;
    if (gn >= DV) return;
    size_t base = (size_t)gn * FLATN + k0 + kq * 16;
    bf16x8 vh0, vh1, vl0, vl1;
#pragma unroll
    for (int j = 0; j < 8; ++j) {
        float w0 = lds[kq * 16 + j][nl];
        u16 h0 = f2bf(w0);
        vh0[j] = (short)h0; vl0[j] = (short)f2bf(w0 - bf2f(h0));
        float w1 = lds[kq * 16 + 8 + j][nl];
        u16 h1 = f2bf(w1);
        vh1[j] = (short)h1; vl1[j] = (short)f2bf(w1 - bf2f(h1));
    }
    *reinterpret_cast<bf16x8*>(Wth + base)     = vh0;
    *reinterpret_cast<bf16x8*>(Wth + base + 8) = vh1;
    *reinterpret_cast<bf16x8*>(Wtl + base)     = vl0;
    *reinterpret_cast<bf16x8*>(Wtl + base + 8) = vl1;
}

// ---------------- chequer gather + bn0 partial sums ----------------
__global__ void k_cheq(const float* __restrict__ ent, const float* __restrict__ rel_out,
                       const int* __restrict__ sub, const int* __restrict__ rel,
                       const int* __restrict__ perm, float* __restrict__ cheq,
                       float* __restrict__ p0) {
    int b = blockIdx.x;
    int sb = sub[b], rb = rel[b];
    __shared__ float rs[256], rss[256];
    float s = 0.f, ss = 0.f;
    for (int i = threadIdx.x; i < 400; i += 256) {
        int p = perm[i];
        float v = (p < DV) ? ent[(size_t)sb * DV + p] : rel_out[(size_t)rb * DV + (p - DV)];
        cheq[(size_t)b * 400 + i] = v;
        s += v; ss += v * v;
    }
    rs[threadIdx.x] = s; rss[threadIdx.x] = ss;
    __syncthreads();
    for (int o = 128; o > 0; o >>= 1) {
        if (threadIdx.x < o) { rs[threadIdx.x] += rs[threadIdx.x + o]; rss[threadIdx.x] += rss[threadIdx.x + o]; }
        __syncthreads();
    }
    if (threadIdx.x == 0) { p0[b] = rs[0]; p0[BB + b] = rss[0]; }
}

// ---------------- reduce bn0 partials ----------------
__global__ void k_red_bn0(const float* __restrict__ p0, float* __restrict__ st) {
    __shared__ float rs[256], rss[256];
    float s = 0.f, ss = 0.f;
    for (int i = threadIdx.x; i < BB; i += 256) { s += p0[i]; ss += p0[BB + i]; }
    rs[threadIdx.x] = s; rss[threadIdx.x] = ss;
    __syncthreads();
    for (int o = 128; o > 0; o >>= 1) {
        if (threadIdx.x < o) { rs[threadIdx.x] += rs[threadIdx.x + o]; rss[threadIdx.x] += rss[threadIdx.x + o]; }
        __syncthreads();
    }
    if (threadIdx.x == 0) { st[0] = rs[0]; st[1] = rss[0]; }
}

// ---------------- conv 9x9 circular via MFMA (im2col-on-the-fly) ----------------
// Per image: C[400 pos][96 filt] = A[400][81] @ filt^T[81][96], K padded to 96.
// 3-term hi/lo bf16 on both operands (error ~2^-17, below old fp32+bf16-store).
// 4 waves split 25 m-frags (7/6/6/6); 2 m-frags per iter amortize B ds_reads.
// filt LDS pitch 104 bf16 (13x16B slots, odd -> conflict-free-ish b128 reads).
__global__ __launch_bounds__(256) void k_conv(const float* __restrict__ cheq,
                                              const float* __restrict__ st,
                                              const float* __restrict__ g0, const float* __restrict__ b0,
                                              const float* __restrict__ filt,
                                              __hip_bfloat16* __restrict__ xconv,
                                              float* __restrict__ chp) {
    int t = threadIdx.x, b = blockIdx.x;
    __shared__ float pad[784];         // 28x28 bn0-applied input
    __shared__ u16 fh[96 * 104];       // filt hi, pitch 104
    __shared__ u16 fl[96 * 104];       // filt lo
    __shared__ float sred[4][192];     // per-wave stats
    const float N0 = (float)BB * 400.f;
    float m0 = st[0] / N0;
    float va = st[1] / N0 - m0 * m0;
    float sg = rsqrtf(va + BEPS) * g0[0];
    float sb = b0[0] - m0 * sg;
    for (int i = t; i < 7776; i += 256) {
        int f = i / 81, q = i - f * 81;
        float wv = filt[i];
        u16 h = f2bf(wv);
        fh[f * 104 + q] = h;
        fl[f * 104 + q] = f2bf(wv - bf2f(h));
    }
    for (int i = t; i < 96 * 15; i += 256) {     // zero k in [81,96)
        int f = i / 15, q = 81 + i % 15;
        fh[f * 104 + q] = 0; fl[f * 104 + q] = 0;
    }
    for (int i = t; i < 784; i += 256) {
        int h = i / 28, w2 = i % 28;
        int r = (h + 16) % 20, c = (w2 + 16) % 20;
        pad[i] = cheq[(size_t)b * 400 + r * 20 + c] * sg + sb;
    }
    __syncthreads();
    int w = t >> 6, lane = t & 63;
    int lrow = lane & 15, lkg = lane >> 4;
    int mfBeg = (w == 0) ? 0 : (1 + 6 * w);   // 0,7,13,19
    int mfEnd = mfBeg + ((w == 0) ? 7 : 6);
    float cs[6] = {}, css[6] = {};
    u16* xb = (u16*)xconv + (size_t)b * FLATN;
    for (int mf = mfBeg; mf < mfEnd; mf += 2) {
        bool two = (mf + 1 < mfEnd);
        // A-fragments for up to 2 m-frags (im2col on the fly from pad)
        bf16x8 ah[2][3], al[2][3];
#pragma unroll
        for (int im = 0; im < 2; ++im) {
            int mfi = (im && !two) ? mf : (mf + im);
            int p = mfi * 16 + lrow;           // < 400 guaranteed
            int y = p / 20, x = p - (p / 20) * 20;
            int pb = y * 28 + x;
#pragma unroll
            for (int ks = 0; ks < 3; ++ks) {
                bf16x8 vh, vl;
#pragma unroll
                for (int j = 0; j < 8; ++j) {
                    int k = ks * 32 + lkg * 8 + j;
                    int dy = (k * 57) >> 9;            // exact k/9 for k<96
                    int dx = k - 9 * dy;
                    float v = (ks < 2 || k < 81) ? pad[pb + dy * 28 + dx] : 0.f;
                    u16 h = f2bf(v);
                    vh[j] = (short)h;
                    vl[j] = (short)f2bf(v - bf2f(h));
                }
                ah[im][ks] = vh; al[im][ks] = vl;
            }
        }
        f32x4 acc0[6] = {}, acc1[6] = {};
#pragma unroll
        for (int nt = 0; nt < 6; ++nt) {
            int fb = (nt * 16 + lrow) * 104;
#pragma unroll
            for (int ks = 0; ks < 3; ++ks) {
                bf16x8 bh = *reinterpret_cast<const bf16x8*>(fh + fb + ks * 32 + lkg * 8);
                bf16x8 bl = *reinterpret_cast<const bf16x8*>(fl + fb + ks * 32 + lkg * 8);
                acc0[nt] = __builtin_amdgcn_mfma_f32_16x16x32_bf16(ah[0][ks], bh, acc0[nt], 0, 0, 0);
                acc0[nt] = __builtin_amdgcn_mfma_f32_16x16x32_bf16(al[0][ks], bh, acc0[nt], 0, 0, 0);
                acc0[nt] = __builtin_amdgcn_mfma_f32_16x16x32_bf16(ah[0][ks], bl, acc0[nt], 0, 0, 0);
                if (two) {
                    acc1[nt] = __builtin_amdgcn_mfma_f32_16x16x32_bf16(ah[1][ks], bh, acc1[nt], 0, 0, 0);
                    acc1[nt] = __builtin_amdgcn_mfma_f32_16x16x32_bf16(al[1][ks], bh, acc1[nt], 0, 0, 0);
                    acc1[nt] = __builtin_amdgcn_mfma_f32_16x16x32_bf16(ah[1][ks], bl, acc1[nt], 0, 0, 0);
                }
            }
        }
        // stats + stores (C layout: col f = lrow-part, rows p = lkg*4+i)
#pragma unroll
        for (int nt = 0; nt < 6; ++nt) {
            int f = nt * 16 + lrow;
            int p0 = mf * 16 + lkg * 4;
            u16x4 o;
#pragma unroll
            for (int i = 0; i < 4; ++i) {
                float v = acc0[nt][i];
                cs[nt] += v; css[nt] += v * v;
                o[i] = f2bf(v);
            }
            *reinterpret_cast<u16x4*>(xb + f * 400 + p0) = o;
            if (two) {
                int p1 = (mf + 1) * 16 + lkg * 4;
                u16x4 o1;
#pragma unroll
                for (int i = 0; i < 4; ++i) {
                    float v = acc1[nt][i];
                    cs[nt] += v; css[nt] += v * v;
                    o1[i] = f2bf(v);
                }
                *reinterpret_cast<u16x4*>(xb + f * 400 + p1) = o1;
            }
        }
    }
    // reduce stats over lkg lanes (lane^16, lane^32 flip lkg bits)
#pragma unroll
    for (int nt = 0; nt < 6; ++nt) {
        cs[nt] += __shfl_xor(cs[nt], 16);  cs[nt] += __shfl_xor(cs[nt], 32);
        css[nt] += __shfl_xor(css[nt], 16); css[nt] += __shfl_xor(css[nt], 32);
    }
    if (lane < 16) {
#pragma unroll
        for (int nt = 0; nt < 6; ++nt) {
            sred[w][nt * 16 + lane] = cs[nt];
            sred[w][96 + nt * 16 + lane] = css[nt];
        }
    }
    __syncthreads();
    if (t < 192) {
        float sum = sred[0][t] + sred[1][t] + sred[2][t] + sred[3][t];
        chp[(size_t)b * 192 + t] = sum;
    }
}

// ---------------- finalize bn1 per-channel scale/bias ----------------
__global__ void k_bn1_final(const float* __restrict__ chp, const float* __restrict__ g1,
                            const float* __restrict__ b1, float* __restrict__ sc,
                            float* __restrict__ bi) {
    int c = blockIdx.x;
    __shared__ float rs[256], rss[256];
    float s = 0.f, ss = 0.f;
    for (int b = threadIdx.x; b < BB; b += 256) {
        s += chp[(size_t)b * 192 + c];
        ss += chp[(size_t)b * 192 + 96 + c];
    }
    rs[threadIdx.x] = s; rss[threadIdx.x] = ss;
    __syncthreads();
    for (int o = 128; o > 0; o >>= 1) {
        if (threadIdx.x < o) { rs[threadIdx.x] += rs[threadIdx.x + o]; rss[threadIdx.x] += rss[threadIdx.x + o]; }
        __syncthreads();
    }
    if (threadIdx.x == 0) {
        float N = (float)BB * 400.f;
        float m = rs[0] / N;
        float v = rss[0] / N - m * m;
        float s_ = rsqrtf(v + BEPS) * g1[c];
        sc[c] = s_;
        bi[c] = b1[c] - m * s_;
    }
}

// ---------------- fc via MFMA v4: async global_load_lds staging ----------------
__global__ __launch_bounds__(256) void k_fc_mfma(const u16* __restrict__ X,
        const u16* __restrict__ Wth, const u16* __restrict__ Wtl,
        const float* __restrict__ sc, const float* __restrict__ bi,
        float* __restrict__ outp) {
    __shared__ __align__(16) char blds[53248];   // hi [0,26624), lo [26624,53248)
    int tid = threadIdx.x;
    int w = tid >> 6, lane = tid & 63;
    int lrow = lane & 15, lkg = lane >> 4;
    int mw = blockIdx.x * 128 + w * 32;
    int kbase = blockIdx.y * 1280;
    f32x4 acc[2][13] = {};
    for (int it = 0; it < 20; ++it) {
        int k0 = kbase + it * 64;
        __syncthreads();   // previous compute done before overwrite
        // A raw loads first (so transform's vmcnt wait leaves staging in flight)
        bf16x8 araw[2][2];
#pragma unroll
        for (int mf = 0; mf < 2; ++mf)
#pragma unroll
            for (int kt = 0; kt < 2; ++kt) {
                int r = mw + mf * 16 + lrow;
                int kk = k0 + kt * 32 + lkg * 8;
                araw[mf][kt] = *reinterpret_cast<const bf16x8*>(X + (size_t)r * FLATN + kk);
            }
        // async stage W hi/lo: dest linear idx*16, source pre-swizzled
#pragma unroll
        for (int q = 0; q < 7; ++q) {
            int bidx = q * 256 + w * 64;      // wave-uniform
            if (bidx < 1600) {
                int idx = bidx + lane;
                int n = idx >> 3;
                int slot = (idx & 7) ^ (n & 7);
                size_t gsrc = (size_t)n * FLATN + k0 + slot * 8;
                gl_lds16(Wth + gsrc, blds + bidx * 16);
                gl_lds16(Wtl + gsrc, blds + 26624 + bidx * 16);
            }
        }
        // A transform (overlaps staging latency)
        bf16x8 ah[2][2], al[2][2];
#pragma unroll
        for (int mf = 0; mf < 2; ++mf)
#pragma unroll
            for (int kt = 0; kt < 2; ++kt) {
                int kk = k0 + kt * 32 + lkg * 8;
                int c = kk / 400;
                float s_ = sc[c], b_ = bi[c];
                bf16x8 fh2, fl2;
#pragma unroll
                for (int j = 0; j < 8; ++j) {
                    float v = bf2f((u16)araw[mf][kt][j]);
                    v = fmaxf(fmaf(v, s_, b_), 0.f);
                    u16 h = f2bf(v);
                    fh2[j] = (short)h;
                    fl2[j] = (short)f2bf(v - bf2f(h));
                }
                ah[mf][kt] = fh2;
                al[mf][kt] = fl2;
            }
        __syncthreads();   // staged tile visible (vmcnt drained here)
#pragma unroll
        for (int nt = 0; nt < 13; ++nt) {
            int n = nt * 16 + lrow;
            int row = n * 128, nx = n & 7;
            int off0 = row + ((lkg ^ nx) << 4);
            int off1 = row + (((4 + lkg) ^ nx) << 4);
            bf16x8 bh0 = *reinterpret_cast<const bf16x8*>(blds + off0);
            bf16x8 bh1 = *reinterpret_cast<const bf16x8*>(blds + off1);
            bf16x8 bl0 = *reinterpret_cast<const bf16x8*>(blds + 26624 + off0);
            bf16x8 bl1 = *reinterpret_cast<const bf16x8*>(blds + 26624 + off1);
#pragma unroll
            for (int mf = 0; mf < 2; ++mf) {
                acc[mf][nt] = __builtin_amdgcn_mfma_f32_16x16x32_bf16(ah[mf][0], bh0, acc[mf][nt], 0, 0, 0);
                acc[mf][nt] = __builtin_amdgcn_mfma_f32_16x16x32_bf16(ah[mf][1], bh1, acc[mf][nt], 0, 0, 0);
                acc[mf][nt] = __builtin_amdgcn_mfma_f32_16x16x32_bf16(ah[mf][0], bl0, acc[mf][nt], 0, 0, 0);
                acc[mf][nt] = __builtin_amdgcn_mfma_f32_16x16x32_bf16(ah[mf][1], bl1, acc[mf][nt], 0, 0, 0);
                acc[mf][nt] = __builtin_amdgcn_mfma_f32_16x16x32_bf16(al[mf][0], bh0, acc[mf][nt], 0, 0, 0);
                acc[mf][nt] = __builtin_amdgcn_mfma_f32_16x16x32_bf16(al[mf][1], bh1, acc[mf][nt], 0, 0, 0);
            }
        }
    }
#pragma unroll
    for (int mf = 0; mf < 2; ++mf)
#pragma unroll
        for (int nt = 0; nt < 13; ++nt) {
            int col = nt * 16 + lrow;
            if (col < DV) {
#pragma unroll
                for (int i = 0; i < 4; ++i) {
                    int r = mw + mf * 16 + lkg * 4 + i;
                    unsafeAtomicAdd(&outp[(size_t)r * DV + col], acc[mf][nt][i]);
                }
            }
        }
}

// ---------------- scores via MFMA v3: async global_load_lds staging ----------------
__global__ __launch_bounds__(256) void k_sc_mfma(const u16* __restrict__ Yh, const u16* __restrict__ Yl,
        const u16* __restrict__ Eh, const u16* __restrict__ El,
        const float* __restrict__ bias, float* __restrict__ outp) {
    __shared__ __align__(16) char elds[32768];   // hi [0,16384), lo [16384,32768)
    int tid = threadIdx.x;
    int w = tid >> 6, lane = tid & 63;
    int lrow = lane & 15, lkg = lane >> 4;
    int mw = blockIdx.x * 128 + w * 32;
    int bn = blockIdx.y * 256;
    f32x4 acc[2][16] = {};
    bf16x8 zv = {};
    for (int kt = 0; kt < 7; ++kt) {
        int kbase = kt * 32;
        __syncthreads();   // protect previous chunk's reads
        // A fragments first
        int kk = kbase + lkg * 8;
        bool kval = (kt < 6) || (lkg < 2);
        bf16x8 ah[2], al[2];
#pragma unroll
        for (int mf = 0; mf < 2; ++mf) {
            int r = mw + mf * 16 + lrow;
            size_t off = (size_t)r * 208 + kk;
            ah[mf] = kval ? *reinterpret_cast<const bf16x8*>(Yh + off) : zv;
            al[mf] = kval ? *reinterpret_cast<const bf16x8*>(Yl + off) : zv;
        }
        // async stage E hi/lo chunk: 1024 slots per term, linear dest
#pragma unroll
        for (int q = 0; q < 4; ++q) {
            int bidx = q * 256 + w * 64;      // wave-uniform
            int idx = bidx + lane;
            int n = idx >> 2;
            int slot = (idx & 3) ^ (n & 3);
            int gn = bn + n; if (gn > N_ENT - 1) gn = N_ENT - 1;
            size_t gsrc = (size_t)gn * 208 + kbase + slot * 8;
            gl_lds16(Eh + gsrc, elds + bidx * 16);
            gl_lds16(El + gsrc, elds + 16384 + bidx * 16);
        }
        __syncthreads();   // staged tile visible
#pragma unroll
        for (int nt = 0; nt < 16; ++nt) {
            int n = nt * 16 + lrow;
            int off = n * 64 + ((lkg ^ (n & 3)) << 4);
            bf16x8 bh = *reinterpret_cast<const bf16x8*>(elds + off);
            bf16x8 bl = *reinterpret_cast<const bf16x8*>(elds + 16384 + off);
            acc[0][nt] = __builtin_amdgcn_mfma_f32_16x16x32_bf16(ah[0], bh, acc[0][nt], 0, 0, 0);
            acc[0][nt] = __builtin_amdgcn_mfma_f32_16x16x32_bf16(ah[0], bl, acc[0][nt], 0, 0, 0);
            acc[0][nt] = __builtin_amdgcn_mfma_f32_16x16x32_bf16(al[0], bh, acc[0][nt], 0, 0, 0);
            acc[1][nt] = __builtin_amdgcn_mfma_f32_16x16x32_bf16(ah[1], bh, acc[1][nt], 0, 0, 0);
            acc[1][nt] = __builtin_amdgcn_mfma_f32_16x16x32_bf16(ah[1], bl, acc[1][nt], 0, 0, 0);
            acc[1][nt] = __builtin_amdgcn_mfma_f32_16x16x32_bf16(al[1], bh, acc[1][nt], 0, 0, 0);
        }
    }
#pragma unroll
    for (int mf = 0; mf < 2; ++mf)
#pragma unroll
        for (int nt = 0; nt < 16; ++nt) {
            int col = bn + nt * 16 + lrow;
            if (col < N_ENT) {
                float bv = bias[col];
#pragma unroll
                for (int i = 0; i < 4; ++i) {
                    int r = mw + mf * 16 + lkg * 4 + i;
                    float s = acc[mf][nt][i] + bv;
                    outp[(size_t)r * N_ENT + col] = 1.f / (1.f + expf(-s));
                }
            }
        }
}

extern "C" void kernel_launch(void* const* d_in, const int* in_sizes, int n_in,
                              void* d_out, int out_size, void* d_ws, size_t ws_size,
                              hipStream_t stream) {
    const float* init_embed = (const float*)d_in[0];
    const float* init_rel   = (const float*)d_in[1];
    const float* loop_rel   = (const float*)d_in[2];
    const float* w_in   = (const float*)d_in[3];
    const float* w_out  = (const float*)d_in[4];
    const float* w_loop = (const float*)d_in[5];
    const float* w_rel  = (const float*)d_in[6];
    const float* att_in  = (const float*)d_in[7];
    const float* att_out = (const float*)d_in[8];
    const float* bnc_g = (const float*)d_in[9];
    const float* bnc_b = (const float*)d_in[10];
    const float* filt  = (const float*)d_in[11];
    const float* g0 = (const float*)d_in[12];
    const float* b0 = (const float*)d_in[13];
    const float* g1 = (const float*)d_in[14];
    const float* b1 = (const float*)d_in[15];
    const float* fc_w = (const float*)d_in[16];
    // d_in[17] fc_b: provably cancelled by bn2's mean subtraction
    const float* g2 = (const float*)d_in[18];
    const float* b2 = (const float*)d_in[19];
    const float* bias = (const float*)d_in[20];
    const int* eidx  = (const int*)d_in[21];
    const int* etype = (const int*)d_in[22];
    const int* sub   = (const int*)d_in[23];
    const int* rel   = (const int*)d_in[24];
    const int* perm  = (const int*)d_in[25];

    float* ws = (float*)d_ws;
    float* outp = (float*)d_out;
    if (ws_size < WS_WORDS * sizeof(float)) return;

    float* s_all  = ws + OFF_S;
    u32*   eid    = (u32*)(ws + OFF_EID);
    u32*   cnt    = (u32*)(ws + OFF_CNT);
    u32*   offs   = (u32*)(ws + OFF_OFFS);
    float* aggC   = ws + OFF_AGG;
    float* fc_out = ws + OFF_FC;
    float* v      = ws + OFF_V;
    float* embl   = ws + OFF_EMB;
    float* epre   = ws + OFF_EPRE;
    float* ent    = ws + OFF_ENT;
    float* relo   = ws + OFF_RELO;
    float* cm     = ws + OFF_CM;
    float* cv     = ws + OFF_CV;
    float* cheq   = ws + OFF_CHEQ;
    float* p0     = ws + OFF_P0;
    float* st0    = ws + OFF_ST0;
    float* chp    = ws + OFF_CHP;
    float* b1sc   = ws + OFF_B1SC;
    float* b1bi   = ws + OFF_B1BI;
    u16*   Wth    = (u16*)(ws + OFF_WTH);
    u16*   Wtl    = (u16*)(ws + OFF_WTL);
    u16*   entH   = (u16*)(ws + OFF_ENTH);
    u16*   entL   = (u16*)(ws + OFF_ENTL);
    u16*   Yh     = (u16*)(ws + OFF_YH);
    u16*   Yl     = (u16*)(ws + OFF_YL);
    __hip_bfloat16* xconv = (__hip_bfloat16*)(ws + OFF_XC);

    // zero counts + agg + fc regions
    hipMemsetAsync(ws + ZERO_BEG, 0, (ZERO_END - ZERO_BEG) * sizeof(float), stream);

    k_vatt<<<2, 256, 0, stream>>>(w_in, w_out, att_in, att_out, v);

    int edge_wave_blocks = (N_EDGE + 3) / 4;   // 4 waves per 256-thread block
    k_edge_score<<<edge_wave_blocks, 256, 0, stream>>>(init_embed, init_rel, eidx, etype, v, s_all);

    int eb = (N_EDGE + 255) / 256;
    k_hist<<<eb, 256, 0, stream>>>(eidx, cnt);
    k_scan<<<1, 256, 0, stream>>>(cnt, offs);
    k_scatter<<<eb, 256, 0, stream>>>(eidx, cnt, eid);
    k_seg_agg<<<(NSEG + 3) / 4, 256, 0, stream>>>(init_embed, init_rel, eidx, etype,
                                                  s_all, offs, eid, aggC);

    k_embloop<<<((size_t)N_ENT * DV + 255) / 256, 256, 0, stream>>>(init_embed, loop_rel, embl);

    dim3 gE((N_ENT + 63) / 64, (DV + 63) / 64);
    gemm_nn<<<gE, 256, 0, stream>>>(aggC,                       w_in,   epre, N_ENT, DV, DV, 0);
    gemm_nn<<<gE, 256, 0, stream>>>(aggC + (size_t)N_ENT * DV,  w_out,  epre, N_ENT, DV, DV, 1);
    gemm_nn<<<gE, 256, 0, stream>>>(embl,                       w_loop, epre, N_ENT, DV, DV, 1);
    dim3 gR((474 + 63) / 64, (DV + 63) / 64);
    gemm_nn<<<gR, 256, 0, stream>>>(init_rel, w_rel, relo, 474, DV, DV, 0);

    // bn over ent_pre (= 3*ent): /3 folded into eps -> 9*EPS (exact)
    k_colstats<<<DV, 256, 0, stream>>>(epre, N_ENT, cm, cv);
    k_bn_ent<<<((size_t)N_ENT * 208 + 255) / 256, 256, 0, stream>>>(
        epre, cm, cv, bnc_g, bnc_b, ent, entH, entL);

    // Wt split (after edge/gemm regions are dead; before fc)
    dim3 gW(FLATN / 64, 4);
    k_wt<<<gW, 256, 0, stream>>>(fc_w, Wth, Wtl);

    k_cheq<<<BB, 256, 0, stream>>>(ent, relo, sub, rel, perm, cheq, p0);
    k_red_bn0<<<1, 256, 0, stream>>>(p0, st0);
    k_conv<<<BB, 256, 0, stream>>>(cheq, st0, g0, b0, filt, xconv, chp);
    k_bn1_final<<<NF, 256, 0, stream>>>(chp, g1, b1, b1sc, b1bi);

    dim3 gFC(16, 30);
    k_fc_mfma<<<gFC, 256, 0, stream>>>((const u16*)xconv, Wth, Wtl, b1sc, b1bi, fc_out);

    k_colstats<<<DV, 256, 0, stream>>>(fc_out, BB, cm, cv);
    k_bn2y<<<((size_t)BB * 208 + 255) / 256, 256, 0, stream>>>(fc_out, cm, cv, g2, b2, Yh, Yl);

    dim3 gS(16, 57);
    k_sc_mfma<<<gS, 256, 0, stream>>>(Yh, Yl, entH, entL, bias, outp);
}

// Round 13
// 1151.637 us; speedup vs baseline: 1.0844x; 1.0844x over previous
//
#include <hip/hip_runtime.h>
#include <hip/hip_bf16.h>

constexpr int DV     = 200;
constexpr int N_ENT  = 14541;
constexpr int N_EDGE = 544230;
constexpr int HALF_E = N_EDGE / 2;
constexpr int NSEG   = 2 * N_ENT;
constexpr int BB     = 2048;
constexpr int NF     = 96;
constexpr int FLATN  = 38400;
constexpr float LEAK = 0.2f;
constexpr float BEPS = 1e-5f;

typedef unsigned int u32;
typedef unsigned short u16;
typedef __attribute__((ext_vector_type(8))) short bf16x8;
typedef __attribute__((ext_vector_type(4))) float f32x4;
typedef __attribute__((ext_vector_type(4))) unsigned short u16x4;

// ---------------- workspace layout (in 4-byte words) ----------------
constexpr size_t OFF_S    = 0;                       // 544230 edge scores
constexpr size_t OFF_EID  = 544230;                  // 544230 CSR edge ids
constexpr size_t OFF_CNT  = 1088460;                 // 29082 u32 counts/fill-ptrs (zeroed)
constexpr size_t OFF_OFFS = 1117542;                 // 29082 u32 seg offsets
constexpr size_t OFF_AGG  = 1146624;                 // 2*14541*200 (zeroed)
constexpr size_t OFF_FC   = 6963218;                 // 2048*200 (zeroed)
constexpr size_t ZERO_BEG = OFF_CNT;
constexpr size_t ZERO_END = OFF_FC + 409600;         // 7372818
constexpr size_t OFF_V    = 7372818;                 // 400 (v_in|v_out)
// --- reused (dead) regions ---
constexpr size_t OFF_WTH  = 0;                        // 200*38400 bf16 = 3,840,000 w
constexpr size_t OFF_ENTH = 3840000;                  // 14541*208 bf16 = 1,512,264 w
constexpr size_t OFF_ENTL = 5352264;                  // 1,512,264 w (end 6,864,528)
constexpr size_t OFF_WTL  = 7373220;                  // 3,840,000 w (end 11,213,220) 16B-aligned
constexpr size_t OFF_EPRE = 10281418;                 // 14541*200 ent pre-bn
constexpr size_t OFF_ENT  = 13189618;                 // 14541*200 ent final (f32)
constexpr size_t OFF_RELO = 16097818;                 // 474*200 rel_out
constexpr size_t OFF_CM   = 16192618;                 // 200 col means
constexpr size_t OFF_CV   = 16192818;                 // 200 col vars
constexpr size_t OFF_CHEQ = 16193018;                 // 2048*400 (dead after conv)
constexpr size_t OFF_WT3H = 16193018;                 // 3*200*224 u16 (+pad) = 68100 w (aliases cheq, pre-cheq)
constexpr size_t OFF_WT3L = 16261118;                 // 68100 w (end 16,329,218)
constexpr size_t OFF_YH   = 16193020;                 // 2048*208 bf16 (aliases cheq, post-fc)
constexpr size_t OFF_YL   = 16406012;                 // 212,992 w (end 16,619,004)
constexpr size_t OFF_P0   = 17012218;                 // 4096 bn0 partials
constexpr size_t OFF_ST0  = 17016314;                 // 2 bn0 stats
constexpr size_t OFF_CHP  = 17016316;                 // 2048*192 bn1 partials
constexpr size_t OFF_B1SC = 17409532;                 // 96
constexpr size_t OFF_B1BI = 17409628;                 // 96
constexpr size_t OFF_XC   = 17819324;                 // bf16 conv out: 39321600 words
constexpr size_t WS_WORDS = OFF_XC + 39321600;

__device__ inline float bf2f(u16 u) { return __uint_as_float(((u32)u) << 16); }
__device__ inline u16 f2bf(float f) {
    __hip_bfloat16 h = __float2bfloat16(f);
    return *reinterpret_cast<u16*>(&h);
}
// async global->LDS 16B (dest = wave-uniform base + lane*16; source per-lane)
__device__ inline void gl_lds16(const void* g, void* l) {
    __builtin_amdgcn_global_load_lds(
        (const __attribute__((address_space(1))) void*)g,
        (__attribute__((address_space(3))) void*)l, 16, 0, 0);
}

// ---------------- tiny: v = W @ att for both directions ----------------
__global__ void k_vatt(const float* __restrict__ w_in, const float* __restrict__ w_out,
                       const float* __restrict__ att_in, const float* __restrict__ att_out,
                       float* __restrict__ v) {
    int t = blockIdx.x * 256 + threadIdx.x;
    if (t < DV) {
        float s = 0.f;
        for (int j = 0; j < DV; ++j) s += w_in[t * DV + j] * att_in[j];
        v[t] = s;
    } else if (t < 2 * DV) {
        int k = t - DV;
        float s = 0.f;
        for (int j = 0; j < DV; ++j) s += w_out[k * DV + j] * att_out[j];
        v[t] = s;
    }
}

// ---------------- edge pass A: score only (no atomics) ----------------
__global__ void k_edge_score(const float* __restrict__ embed, const float* __restrict__ rel,
                             const int* __restrict__ eidx, const int* __restrict__ etype,
                             const float* __restrict__ v, float* __restrict__ s_all) {
    int gw = (blockIdx.x * 256 + threadIdx.x) >> 6;
    int lane = threadIdx.x & 63;
    if (gw >= N_EDGE) return;
    int e = gw;
    int dst = eidx[N_EDGE + e], et = etype[e];
    int dir = (e >= HALF_E);
    const float* vv = v + dir * DV;
    const float* er = embed + (size_t)dst * DV;
    const float* rr = rel + (size_t)et * DV;
    float acc = 0.f;
    for (int d = lane; d < DV; d += 64) acc += er[d] * rr[d] * vv[d];
    for (int off = 32; off > 0; off >>= 1) acc += __shfl_down(acc, off);
    if (lane == 0) {
        float s = acc > 0.f ? acc : LEAK * acc;
        s_all[e] = s;
    }
}

// ---------------- CSR build: histogram ----------------
__global__ void k_hist(const int* __restrict__ eidx, u32* __restrict__ cnt) {
    int e = blockIdx.x * 256 + threadIdx.x;
    if (e >= N_EDGE) return;
    int seg = (e >= HALF_E ? N_ENT : 0) + eidx[e];
    atomicAdd(&cnt[seg], 1u);
}

// ---------------- CSR build: single-block exclusive scan ----------------
__global__ void k_scan(u32* __restrict__ cnt, u32* __restrict__ offs) {
    __shared__ u32 s[256];
    __shared__ u32 base;
    if (threadIdx.x == 0) base = 0;
    __syncthreads();
    for (int c0 = 0; c0 < NSEG; c0 += 256) {
        int i = c0 + threadIdx.x;
        u32 vv = (i < NSEG) ? cnt[i] : 0;
        s[threadIdx.x] = vv;
        __syncthreads();
        for (int o = 1; o < 256; o <<= 1) {
            u32 t = (threadIdx.x >= (u32)o) ? s[threadIdx.x - o] : 0u;
            __syncthreads();
            s[threadIdx.x] += t;
            __syncthreads();
        }
        u32 exc = base + s[threadIdx.x] - vv;
        if (i < NSEG) { offs[i] = exc; cnt[i] = exc; }
        __syncthreads();
        if (threadIdx.x == 255) base += s[255];
        __syncthreads();
    }
}

// ---------------- CSR build: scatter edge ids ----------------
__global__ void k_scatter(const int* __restrict__ eidx, u32* __restrict__ pos,
                          u32* __restrict__ eid) {
    int e = blockIdx.x * 256 + threadIdx.x;
    if (e >= N_EDGE) return;
    int seg = (e >= HALF_E ? N_ENT : 0) + eidx[e];
    u32 slot = atomicAdd(&pos[seg], 1u);
    eid[slot] = (u32)e;
}

// ---------------- fused segment softmax + aggregation (1 wave / segment) ----------------
__global__ void k_seg_agg(const float* __restrict__ embed, const float* __restrict__ rel,
                          const int* __restrict__ eidx, const int* __restrict__ etype,
                          const float* __restrict__ s_all, const u32* __restrict__ offs,
                          const u32* __restrict__ eid, float* __restrict__ aggC) {
    int gw = (blockIdx.x * 256 + threadIdx.x) >> 6;
    int lane = threadIdx.x & 63;
    if (gw >= NSEG) return;
    u32 beg = offs[gw];
    u32 end = (gw == NSEG - 1) ? (u32)N_EDGE : offs[gw + 1];
    int deg = (int)(end - beg);
    if (deg == 0) return;
    float m = -1e30f;
    for (int i = lane; i < deg; i += 64) m = fmaxf(m, s_all[eid[beg + i]]);
    for (int o = 32; o > 0; o >>= 1) m = fmaxf(m, __shfl_xor(m, o));
    float dsum = 0.f;
    for (int i = lane; i < deg; i += 64) dsum += expf(s_all[eid[beg + i]] - m);
    for (int o = 32; o > 0; o >>= 1) dsum += __shfl_xor(dsum, o);
    float inv = 1.f / (dsum + 1e-16f);
    float a0 = 0.f, a1 = 0.f, a2 = 0.f, a3 = 0.f;
    bool t3 = (lane < 8);
    for (int j = 0; j < deg; ++j) {
        int e = (int)eid[beg + j];
        float alpha = expf(s_all[e] - m) * inv;
        int dst = eidx[N_EDGE + e], et = etype[e];
        const float* er = embed + (size_t)dst * DV;
        const float* rr = rel + (size_t)et * DV;
        float p0 = er[lane] * rr[lane];
        float p1 = er[lane + 64] * rr[lane + 64];
        float p2 = er[lane + 128] * rr[lane + 128];
        float p3 = t3 ? er[lane + 192] * rr[lane + 192] : 0.f;
        a0 = fmaf(p0, alpha, a0);
        a1 = fmaf(p1, alpha, a1);
        a2 = fmaf(p2, alpha, a2);
        a3 = fmaf(p3, alpha, a3);
    }
    float* ag = aggC + (size_t)gw * DV;
    ag[lane] = a0;
    ag[lane + 64] = a1;
    ag[lane + 128] = a2;
    if (t3) ag[lane + 192] = a3;
}

// ---------------- generic fp32 GEMM: C (+)= A[MxK] @ B[KxN] (relo only now) ----------------
__global__ void gemm_nn(const float* __restrict__ A, const float* __restrict__ B,
                        float* __restrict__ C, int M, int N, int K, int beta) {
    __shared__ float As[16][65];
    __shared__ float Bs[16][64];
    int bm = blockIdx.x * 64, bn = blockIdx.y * 64;
    int tx = threadIdx.x & 15, ty = threadIdx.x >> 4;
    float acc[4][4] = {};
    for (int k0 = 0; k0 < K; k0 += 16) {
        for (int i = threadIdx.x; i < 1024; i += 256) {
            int m = i >> 4, k = i & 15;
            int gm = bm + m, gk = k0 + k;
            As[k][m] = (gm < M && gk < K) ? A[(size_t)gm * K + gk] : 0.f;
        }
        for (int i = threadIdx.x; i < 1024; i += 256) {
            int k = i >> 6, n = i & 63;
            int gk = k0 + k, gn = bn + n;
            Bs[k][n] = (gk < K && gn < N) ? B[(size_t)gk * N + gn] : 0.f;
        }
        __syncthreads();
#pragma unroll
        for (int k = 0; k < 16; ++k) {
            float a[4], bv[4];
#pragma unroll
            for (int i = 0; i < 4; i++) a[i] = As[k][ty * 4 + i];
#pragma unroll
            for (int j = 0; j < 4; j++) bv[j] = Bs[k][tx * 4 + j];
#pragma unroll
            for (int i = 0; i < 4; i++)
#pragma unroll
                for (int j = 0; j < 4; j++) acc[i][j] += a[i] * bv[j];
        }
        __syncthreads();
    }
#pragma unroll
    for (int i = 0; i < 4; i++) {
        int r = bm + ty * 4 + i;
        if (r >= M) continue;
#pragma unroll
        for (int j = 0; j < 4; j++) {
            int c = bn + tx * 4 + j;
            if (c >= N) continue;
            size_t idx = (size_t)r * N + c;
            C[idx] = beta ? C[idx] + acc[i][j] : acc[i][j];
        }
    }
}

// ---------------- transpose+hi/lo the 3 small weight mats: wT[3][200][224] ----------------
__global__ void k_wt3(const float* __restrict__ w_in, const float* __restrict__ w_out,
                      const float* __restrict__ w_loop,
                      u16* __restrict__ wTh, u16* __restrict__ wTl) {
    int i = blockIdx.x * 256 + threadIdx.x;
    if (i >= 3 * 200 * 224) return;
    int s = i / 44800, rem = i - s * 44800;
    int n = rem / 224, k = rem - n * 224;
    const float* w = (s == 0) ? w_in : (s == 1 ? w_out : w_loop);
    float v = (k < 200) ? w[k * 200 + n] : 0.f;
    u16 h = f2bf(v);
    wTh[i] = h;
    wTl[i] = f2bf(v - bf2f(h));
}

// ---------------- epre via MFMA: sum of 3 segment GEMMs, hi/lo 3-term ----------------
// epre = aggC_in @ w_in + aggC_out @ w_out + (embed*lr) @ w_loop.
// Clone of k_sc_mfma pattern: per (seg,chunk) async-stage B^T chunk, A hi/lo
// split on the fly from f32 (lr folded into seg 2). Garbage B rows n>=200
// only feed discarded cols (col<200 store guard).
__global__ __launch_bounds__(256) void k_epre_mfma(const float* __restrict__ aggC,
        const float* __restrict__ embed, const float* __restrict__ lr,
        const u16* __restrict__ wTh, const u16* __restrict__ wTl,
        float* __restrict__ epre) {
    __shared__ __align__(16) char elds[26624];   // hi [0,13312), lo [13312,26624)
    int tid = threadIdx.x;
    int w = tid >> 6, lane = tid & 63;
    int lrow = lane & 15, lkg = lane >> 4;
    int mw = blockIdx.x * 128 + w * 32;
    f32x4 acc[2][13] = {};
    for (int seg = 0; seg < 3; ++seg) {
        const float* Asrc = (seg == 0) ? aggC : (seg == 1 ? aggC + (size_t)N_ENT * DV : embed);
        const u16* bhg = wTh + seg * 44800;
        const u16* blg = wTl + seg * 44800;
        for (int kt = 0; kt < 7; ++kt) {
            int kb = kt * 32;
            __syncthreads();   // protect previous chunk's reads
            // A fragments: 8 f32 -> hi/lo bf16
            int kk = kb + lkg * 8;
            bool kval = (kt < 6) || (lkg < 1);
            bf16x8 ah[2], al[2];
#pragma unroll
            for (int mf = 0; mf < 2; ++mf) {
                int r = mw + mf * 16 + lrow; if (r > N_ENT - 1) r = N_ENT - 1;
                bf16x8 vh = {}, vl = {};
                if (kval) {
                    const float* ap = Asrc + (size_t)r * DV + kk;
#pragma unroll
                    for (int j = 0; j < 8; ++j) {
                        float v = ap[j];
                        if (seg == 2) v *= lr[kk + j];
                        u16 h = f2bf(v);
                        vh[j] = (short)h;
                        vl[j] = (short)f2bf(v - bf2f(h));
                    }
                }
                ah[mf] = vh; al[mf] = vl;
            }
            // async stage B^T chunk: 832 slots per term (n<208), linear dest
#pragma unroll
            for (int q = 0; q < 4; ++q) {
                int bidx = q * 256 + w * 64;      // wave-uniform
                if (bidx < 832) {
                    int idx = bidx + lane;
                    int n = idx >> 2;
                    int slot = (idx & 3) ^ (n & 3);
                    size_t gsrc = (size_t)n * 224 + kb + slot * 8;
                    gl_lds16(bhg + gsrc, elds + bidx * 16);
                    gl_lds16(blg + gsrc, elds + 13312 + bidx * 16);
                }
            }
            __syncthreads();   // staged tile visible
#pragma unroll
            for (int nt = 0; nt < 13; ++nt) {
                int n = nt * 16 + lrow;
                int off = n * 64 + ((lkg ^ (n & 3)) << 4);
                bf16x8 bh = *reinterpret_cast<const bf16x8*>(elds + off);
                bf16x8 bl = *reinterpret_cast<const bf16x8*>(elds + 13312 + off);
#pragma unroll
                for (int mf = 0; mf < 2; ++mf) {
                    acc[mf][nt] = __builtin_amdgcn_mfma_f32_16x16x32_bf16(ah[mf], bh, acc[mf][nt], 0, 0, 0);
                    acc[mf][nt] = __builtin_amdgcn_mfma_f32_16x16x32_bf16(ah[mf], bl, acc[mf][nt], 0, 0, 0);
                    acc[mf][nt] = __builtin_amdgcn_mfma_f32_16x16x32_bf16(al[mf], bh, acc[mf][nt], 0, 0, 0);
                }
            }
        }
    }
#pragma unroll
    for (int mf = 0; mf < 2; ++mf)
#pragma unroll
        for (int nt = 0; nt < 13; ++nt) {
            int col = nt * 16 + lrow;
            if (col < DV) {
#pragma unroll
                for (int i = 0; i < 4; ++i) {
                    int r = mw + mf * 16 + lkg * 4 + i;
                    if (r < N_ENT) epre[(size_t)r * DV + col] = acc[mf][nt][i];
                }
            }
        }
}

// ---------------- per-column stats over R x 200 ----------------
__global__ void k_colstats(const float* __restrict__ X, int R,
                           float* __restrict__ cm, float* __restrict__ cv) {
    int col = blockIdx.x;
    __shared__ float rs[256], rss[256];
    float s = 0.f, ss = 0.f;
    for (int r = threadIdx.x; r < R; r += 256) {
        float x = X[(size_t)r * DV + col];
        s += x; ss += x * x;
    }
    rs[threadIdx.x] = s; rss[threadIdx.x] = ss;
    __syncthreads();
    for (int o = 128; o > 0; o >>= 1) {
        if (threadIdx.x < o) { rs[threadIdx.x] += rs[threadIdx.x + o]; rss[threadIdx.x] += rss[threadIdx.x + o]; }
        __syncthreads();
    }
    if (threadIdx.x == 0) {
        float m = rs[0] / R;
        cm[col] = m;
        cv[col] = rss[0] / R - m * m;
    }
}

// ---------------- bn(ent): tanh + f32 + bf16 hi/lo (padded pitch 208) ----------------
__global__ void k_bn_ent(const float* __restrict__ epre, const float* __restrict__ cm,
                         const float* __restrict__ cv, const float* __restrict__ g,
                         const float* __restrict__ b, float* __restrict__ ent,
                         u16* __restrict__ eh, u16* __restrict__ el) {
    size_t i = (size_t)blockIdx.x * 256 + threadIdx.x;
    if (i >= (size_t)N_ENT * 208) return;
    int row = (int)(i / 208), col = (int)(i % 208);
    if (col < DV) {
        float val = (epre[(size_t)row * DV + col] - cm[col]) * rsqrtf(cv[col] + 9.f * BEPS) * g[col] + b[col];
        val = tanhf(val);
        ent[(size_t)row * DV + col] = val;
        u16 h = f2bf(val);
        eh[i] = h;
        el[i] = f2bf(val - bf2f(h));
    } else { eh[i] = 0; el[i] = 0; }
}

// ---------------- bn2(fc_out): relu + bf16 hi/lo Y (padded pitch 208) ----------------
__global__ void k_bn2y(const float* __restrict__ fc, const float* __restrict__ cm,
                       const float* __restrict__ cv, const float* __restrict__ g,
                       const float* __restrict__ b, u16* __restrict__ yh,
                       u16* __restrict__ yl) {
    size_t i = (size_t)blockIdx.x * 256 + threadIdx.x;
    if (i >= (size_t)BB * 208) return;
    int row = (int)(i / 208), col = (int)(i % 208);
    if (col < DV) {
        float val = (fc[(size_t)row * DV + col] - cm[col]) * rsqrtf(cv[col] + BEPS) * g[col] + b[col];
        val = fmaxf(val, 0.f);
        u16 h = f2bf(val);
        yh[i] = h;
        yl[i] = f2bf(val - bf2f(h));
    } else { yh[i] = 0; yl[i] = 0; }
}

// ---------------- fc_w transpose + hi/lo split: W[38400][200] -> Wt[200][38400] ----------------
__global__ __launch_bounds__(256) void k_wt(const float* __restrict__ W,
                                            u16* __restrict__ Wth, u16* __restrict__ Wtl) {
    __shared__ float lds[64][65];
    int k0 = blockIdx.x * 64, n0 = blockIdx.y * 64;
    for (int idx = threadIdx.x; idx < 4096; idx += 256) {
        int kl = idx >> 6, nl = idx & 63;
        int gk = k0 + kl, gn = n0 + nl;
        lds[kl][nl] = (gn < DV) ? W[(size_t)gk * DV + gn] : 0.f;
    }
    __syncthreads();
    int nl = threadIdx.x >> 2, kq = threadIdx.x & 3;
    int gn = n0 + nl;
    if (gn >= DV) return;
    size_t base = (size_t)gn * FLATN + k0 + kq * 16;
    bf16x8 vh0, vh1, vl0, vl1;
#pragma unroll
    for (int j = 0; j < 8; ++j) {
        float w0 = lds[kq * 16 + j][nl];
        u16 h0 = f2bf(w0);
        vh0[j] = (short)h0; vl0[j] = (short)f2bf(w0 - bf2f(h0));
        float w1 = lds[kq * 16 + 8 + j][nl];
        u16 h1 = f2bf(w1);
        vh1[j] = (short)h1; vl1[j] = (short)f2bf(w1 - bf2f(h1));
    }
    *reinterpret_cast<bf16x8*>(Wth + base)     = vh0;
    *reinterpret_cast<bf16x8*>(Wth + base + 8) = vh1;
    *reinterpret_cast<bf16x8*>(Wtl + base)     = vl0;
    *reinterpret_cast<bf16x8*>(Wtl + base + 8) = vl1;
}

// ---------------- chequer gather + bn0 partial sums ----------------
__global__ void k_cheq(const float* __restrict__ ent, const float* __restrict__ rel_out,
                       const int* __restrict__ sub, const int* __restrict__ rel,
                       const int* __restrict__ perm, float* __restrict__ cheq,
                       float* __restrict__ p0) {
    int b = blockIdx.x;
    int sb = sub[b], rb = rel[b];
    __shared__ float rs[256], rss[256];
    float s = 0.f, ss = 0.f;
    for (int i = threadIdx.x; i < 400; i += 256) {
        int p = perm[i];
        float v = (p < DV) ? ent[(size_t)sb * DV + p] : rel_out[(size_t)rb * DV + (p - DV)];
        cheq[(size_t)b * 400 + i] = v;
        s += v; ss += v * v;
    }
    rs[threadIdx.x] = s; rss[threadIdx.x] = ss;
    __syncthreads();
    for (int o = 128; o > 0; o >>= 1) {
        if (threadIdx.x < o) { rs[threadIdx.x] += rs[threadIdx.x + o]; rss[threadIdx.x] += rss[threadIdx.x + o]; }
        __syncthreads();
    }
    if (threadIdx.x == 0) { p0[b] = rs[0]; p0[BB + b] = rss[0]; }
}

// ---------------- reduce bn0 partials ----------------
__global__ void k_red_bn0(const float* __restrict__ p0, float* __restrict__ st) {
    __shared__ float rs[256], rss[256];
    float s = 0.f, ss = 0.f;
    for (int i = threadIdx.x; i < BB; i += 256) { s += p0[i]; ss += p0[BB + i]; }
    rs[threadIdx.x] = s; rss[threadIdx.x] = ss;
    __syncthreads();
    for (int o = 128; o > 0; o >>= 1) {
        if (threadIdx.x < o) { rs[threadIdx.x] += rs[threadIdx.x + o]; rss[threadIdx.x] += rss[threadIdx.x + o]; }
        __syncthreads();
    }
    if (threadIdx.x == 0) { st[0] = rs[0]; st[1] = rss[0]; }
}

// ---------------- conv 9x9 circular, 2 images per block (r11 version) ----------------
__global__ __launch_bounds__(384, 4) void k_conv(const float* __restrict__ cheq,
                                              const float* __restrict__ st,
                                              const float* __restrict__ g0, const float* __restrict__ b0,
                                              const float* __restrict__ filt,
                                              __hip_bfloat16* __restrict__ xconv,
                                              float* __restrict__ chp) {
    int t = threadIdx.x;
    int img = t / 192;            // 0 or 1 (wave-aligned split)
    int tl = t - img * 192;
    int b = blockIdx.x * 2 + img;
    __shared__ float pad[2][784];  // 28x28 per image
    __shared__ float flds[7968];   // 96 x 83 (stride 83 -> odd bank step 19)
    __shared__ float red[384];
    for (int i = t; i < 7776; i += 384) {
        int f = i / 81, q = i - f * 81;
        flds[f * 83 + q] = filt[i];
    }
    const float N0 = (float)BB * 400.f;
    float m = st[0] / N0;
    float va = st[1] / N0 - m * m;
    float sg = rsqrtf(va + BEPS) * g0[0];
    float sb = b0[0] - m * sg;
    for (int i = t; i < 1568; i += 384) {
        int im = i / 784, j = i - im * 784;
        int h = j / 28, w2 = j % 28;
        int r = (h + 16) % 20, c = (w2 + 16) % 20;
        pad[im][j] = cheq[(size_t)(blockIdx.x * 2 + im) * 400 + r * 20 + c] * sg + sb;
    }
    __syncthreads();
    int f = tl % 96, hp = tl / 96;
    const float* fbase = flds + f * 83;
    const float* mypad = pad[img];
    float cs = 0.f, css = 0.f;
    u16* xo = (u16*)xconv + (size_t)b * FLATN + f * 400 + hp * 200;
    for (int rt = 0; rt < 10; ++rt) {
        int y = hp * 10 + rt;
        float acc[20];
#pragma unroll
        for (int x = 0; x < 20; ++x) acc[x] = 0.f;
        for (int dy = 0; dy < 9; ++dy) {
            float pr[28];
            const float4* prow = reinterpret_cast<const float4*>(&mypad[(y + dy) * 28]);
#pragma unroll
            for (int qv = 0; qv < 7; ++qv) {
                float4 v4 = prow[qv];
                pr[qv * 4 + 0] = v4.x; pr[qv * 4 + 1] = v4.y;
                pr[qv * 4 + 2] = v4.z; pr[qv * 4 + 3] = v4.w;
            }
            float fw[9];
#pragma unroll
            for (int dx = 0; dx < 9; ++dx) fw[dx] = fbase[dy * 9 + dx];
#pragma unroll
            for (int dx = 0; dx < 9; ++dx)
#pragma unroll
                for (int x = 0; x < 20; ++x)
                    acc[x] = fmaf(pr[x + dx], fw[dx], acc[x]);
        }
#pragma unroll
        for (int x = 0; x < 20; ++x) { cs += acc[x]; css += acc[x] * acc[x]; }
#pragma unroll
        for (int jj = 0; jj < 5; ++jj) {
            u16x4 o;
#pragma unroll
            for (int q2 = 0; q2 < 4; ++q2) o[q2] = f2bf(acc[jj * 4 + q2]);
            *reinterpret_cast<u16x4*>(xo + rt * 20 + jj * 4) = o;
        }
    }
    red[t] = cs; __syncthreads();
    if (tl < 96) chp[(size_t)b * 192 + tl] = red[img * 192 + tl] + red[img * 192 + tl + 96];
    __syncthreads();
    red[t] = css; __syncthreads();
    if (tl < 96) chp[(size_t)b * 192 + 96 + tl] = red[img * 192 + tl] + red[img * 192 + tl + 96];
}

// ---------------- finalize bn1 per-channel scale/bias ----------------
__global__ void k_bn1_final(const float* __restrict__ chp, const float* __restrict__ g1,
                            const float* __restrict__ b1, float* __restrict__ sc,
                            float* __restrict__ bi) {
    int c = blockIdx.x;
    __shared__ float rs[256], rss[256];
    float s = 0.f, ss = 0.f;
    for (int b = threadIdx.x; b < BB; b += 256) {
        s += chp[(size_t)b * 192 + c];
        ss += chp[(size_t)b * 192 + 96 + c];
    }
    rs[threadIdx.x] = s; rss[threadIdx.x] = ss;
    __syncthreads();
    for (int o = 128; o > 0; o >>= 1) {
        if (threadIdx.x < o) { rs[threadIdx.x] += rs[threadIdx.x + o]; rss[threadIdx.x] += rss[threadIdx.x + o]; }
        __syncthreads();
    }
    if (threadIdx.x == 0) {
        float N = (float)BB * 400.f;
        float m = rs[0] / N;
        float v = rss[0] / N - m * m;
        float s_ = rsqrtf(v + BEPS) * g1[c];
        sc[c] = s_;
        bi[c] = b1[c] - m * s_;
    }
}

// ---------------- fc via MFMA v4: async global_load_lds staging ----------------
__global__ __launch_bounds__(256) void k_fc_mfma(const u16* __restrict__ X,
        const u16* __restrict__ Wth, const u16* __restrict__ Wtl,
        const float* __restrict__ sc, const float* __restrict__ bi,
        float* __restrict__ outp) {
    __shared__ __align__(16) char blds[53248];   // hi [0,26624), lo [26624,53248)
    int tid = threadIdx.x;
    int w = tid >> 6, lane = tid & 63;
    int lrow = lane & 15, lkg = lane >> 4;
    int mw = blockIdx.x * 128 + w * 32;
    int kbase = blockIdx.y * 1280;
    f32x4 acc[2][13] = {};
    for (int it = 0; it < 20; ++it) {
        int k0 = kbase + it * 64;
        __syncthreads();   // previous compute done before overwrite
        bf16x8 araw[2][2];
#pragma unroll
        for (int mf = 0; mf < 2; ++mf)
#pragma unroll
            for (int kt = 0; kt < 2; ++kt) {
                int r = mw + mf * 16 + lrow;
                int kk = k0 + kt * 32 + lkg * 8;
                araw[mf][kt] = *reinterpret_cast<const bf16x8*>(X + (size_t)r * FLATN + kk);
            }
#pragma unroll
        for (int q = 0; q < 7; ++q) {
            int bidx = q * 256 + w * 64;      // wave-uniform
            if (bidx < 1600) {
                int idx = bidx + lane;
                int n = idx >> 3;
                int slot = (idx & 7) ^ (n & 7);
                size_t gsrc = (size_t)n * FLATN + k0 + slot * 8;
                gl_lds16(Wth + gsrc, blds + bidx * 16);
                gl_lds16(Wtl + gsrc, blds + 26624 + bidx * 16);
            }
        }
        bf16x8 ah[2][2], al[2][2];
#pragma unroll
        for (int mf = 0; mf < 2; ++mf)
#pragma unroll
            for (int kt = 0; kt < 2; ++kt) {
                int kk = k0 + kt * 32 + lkg * 8;
                int c = kk / 400;
                float s_ = sc[c], b_ = bi[c];
                bf16x8 fh2, fl2;
#pragma unroll
                for (int j = 0; j < 8; ++j) {
                    float v = bf2f((u16)araw[mf][kt][j]);
                    v = fmaxf(fmaf(v, s_, b_), 0.f);
                    u16 h = f2bf(v);
                    fh2[j] = (short)h;
                    fl2[j] = (short)f2bf(v - bf2f(h));
                }
                ah[mf][kt] = fh2;
                al[mf][kt] = fl2;
            }
        __syncthreads();   // staged tile visible (vmcnt drained here)
#pragma unroll
        for (int nt = 0; nt < 13; ++nt) {
            int n = nt * 16 + lrow;
            int row = n * 128, nx = n & 7;
            int off0 = row + ((lkg ^ nx) << 4);
            int off1 = row + (((4 + lkg) ^ nx) << 4);
            bf16x8 bh0 = *reinterpret_cast<const bf16x8*>(blds + off0);
            bf16x8 bh1 = *reinterpret_cast<const bf16x8*>(blds + off1);
            bf16x8 bl0 = *reinterpret_cast<const bf16x8*>(blds + 26624 + off0);
            bf16x8 bl1 = *reinterpret_cast<const bf16x8*>(blds + 26624 + off1);
#pragma unroll
            for (int mf = 0; mf < 2; ++mf) {
                acc[mf][nt] = __builtin_amdgcn_mfma_f32_16x16x32_bf16(ah[mf][0], bh0, acc[mf][nt], 0, 0, 0);
                acc[mf][nt] = __builtin_amdgcn_mfma_f32_16x16x32_bf16(ah[mf][1], bh1, acc[mf][nt], 0, 0, 0);
                acc[mf][nt] = __builtin_amdgcn_mfma_f32_16x16x32_bf16(ah[mf][0], bl0, acc[mf][nt], 0, 0, 0);
                acc[mf][nt] = __builtin_amdgcn_mfma_f32_16x16x32_bf16(ah[mf][1], bl1, acc[mf][nt], 0, 0, 0);
                acc[mf][nt] = __builtin_amdgcn_mfma_f32_16x16x32_bf16(al[mf][0], bh0, acc[mf][nt], 0, 0, 0);
                acc[mf][nt] = __builtin_amdgcn_mfma_f32_16x16x32_bf16(al[mf][1], bh1, acc[mf][nt], 0, 0, 0);
            }
        }
    }
#pragma unroll
    for (int mf = 0; mf < 2; ++mf)
#pragma unroll
        for (int nt = 0; nt < 13; ++nt) {
            int col = nt * 16 + lrow;
            if (col < DV) {
#pragma unroll
                for (int i = 0; i < 4; ++i) {
                    int r = mw + mf * 16 + lkg * 4 + i;
                    unsafeAtomicAdd(&outp[(size_t)r * DV + col], acc[mf][nt][i]);
                }
            }
        }
}

// ---------------- scores via MFMA v3: async global_load_lds staging ----------------
__global__ __launch_bounds__(256) void k_sc_mfma(const u16* __restrict__ Yh, const u16* __restrict__ Yl,
        const u16* __restrict__ Eh, const u16* __restrict__ El,
        const float* __restrict__ bias, float* __restrict__ outp) {
    __shared__ __align__(16) char elds[32768];   // hi [0,16384), lo [16384,32768)
    int tid = threadIdx.x;
    int w = tid >> 6, lane = tid & 63;
    int lrow = lane & 15, lkg = lane >> 4;
    int mw = blockIdx.x * 128 + w * 32;
    int bn = blockIdx.y * 256;
    f32x4 acc[2][16] = {};
    bf16x8 zv = {};
    for (int kt = 0; kt < 7; ++kt) {
        int kbase = kt * 32;
        __syncthreads();   // protect previous chunk's reads
        int kk = kbase + lkg * 8;
        bool kval = (kt < 6) || (lkg < 2);
        bf16x8 ah[2], al[2];
#pragma unroll
        for (int mf = 0; mf < 2; ++mf) {
            int r = mw + mf * 16 + lrow;
            size_t off = (size_t)r * 208 + kk;
            ah[mf] = kval ? *reinterpret_cast<const bf16x8*>(Yh + off) : zv;
            al[mf] = kval ? *reinterpret_cast<const bf16x8*>(Yl + off) : zv;
        }
#pragma unroll
        for (int q = 0; q < 4; ++q) {
            int bidx = q * 256 + w * 64;      // wave-uniform
            int idx = bidx + lane;
            int n = idx >> 2;
            int slot = (idx & 3) ^ (n & 3);
            int gn = bn + n; if (gn > N_ENT - 1) gn = N_ENT - 1;
            size_t gsrc = (size_t)gn * 208 + kbase + slot * 8;
            gl_lds16(Eh + gsrc, elds + bidx * 16);
            gl_lds16(El + gsrc, elds + 16384 + bidx * 16);
        }
        __syncthreads();   // staged tile visible
#pragma unroll
        for (int nt = 0; nt < 16; ++nt) {
            int n = nt * 16 + lrow;
            int off = n * 64 + ((lkg ^ (n & 3)) << 4);
            bf16x8 bh = *reinterpret_cast<const bf16x8*>(elds + off);
            bf16x8 bl = *reinterpret_cast<const bf16x8*>(elds + 16384 + off);
            acc[0][nt] = __builtin_amdgcn_mfma_f32_16x16x32_bf16(ah[0], bh, acc[0][nt], 0, 0, 0);
            acc[0][nt] = __builtin_amdgcn_mfma_f32_16x16x32_bf16(ah[0], bl, acc[0][nt], 0, 0, 0);
            acc[0][nt] = __builtin_amdgcn_mfma_f32_16x16x32_bf16(al[0], bh, acc[0][nt], 0, 0, 0);
            acc[1][nt] = __builtin_amdgcn_mfma_f32_16x16x32_bf16(ah[1], bh, acc[1][nt], 0, 0, 0);
            acc[1][nt] = __builtin_amdgcn_mfma_f32_16x16x32_bf16(ah[1], bl, acc[1][nt], 0, 0, 0);
            acc[1][nt] = __builtin_amdgcn_mfma_f32_16x16x32_bf16(al[1], bh, acc[1][nt], 0, 0, 0);
        }
    }
#pragma unroll
    for (int mf = 0; mf < 2; ++mf)
#pragma unroll
        for (int nt = 0; nt < 16; ++nt) {
            int col = bn + nt * 16 + lrow;
            if (col < N_ENT) {
                float bv = bias[col];
#pragma unroll
                for (int i = 0; i < 4; ++i) {
                    int r = mw + mf * 16 + lkg * 4 + i;
                    float s = acc[mf][nt][i] + bv;
                    outp[(size_t)r * N_ENT + col] = 1.f / (1.f + expf(-s));
                }
            }
        }
}

extern "C" void kernel_launch(void* const* d_in, const int* in_sizes, int n_in,
                              void* d_out, int out_size, void* d_ws, size_t ws_size,
                              hipStream_t stream) {
    const float* init_embed = (const float*)d_in[0];
    const float* init_rel   = (const float*)d_in[1];
    const float* loop_rel   = (const float*)d_in[2];
    const float* w_in   = (const float*)d_in[3];
    const float* w_out  = (const float*)d_in[4];
    const float* w_loop = (const float*)d_in[5];
    const float* w_rel  = (const float*)d_in[6];
    const float* att_in  = (const float*)d_in[7];
    const float* att_out = (const float*)d_in[8];
    const float* bnc_g = (const float*)d_in[9];
    const float* bnc_b = (const float*)d_in[10];
    const float* filt  = (const float*)d_in[11];
    const float* g0 = (const float*)d_in[12];
    const float* b0 = (const float*)d_in[13];
    const float* g1 = (const float*)d_in[14];
    const float* b1 = (const float*)d_in[15];
    const float* fc_w = (const float*)d_in[16];
    // d_in[17] fc_b: provably cancelled by bn2's mean subtraction
    const float* g2 = (const float*)d_in[18];
    const float* b2 = (const float*)d_in[19];
    const float* bias = (const float*)d_in[20];
    const int* eidx  = (const int*)d_in[21];
    const int* etype = (const int*)d_in[22];
    const int* sub   = (const int*)d_in[23];
    const int* rel   = (const int*)d_in[24];
    const int* perm  = (const int*)d_in[25];

    float* ws = (float*)d_ws;
    float* outp = (float*)d_out;
    if (ws_size < WS_WORDS * sizeof(float)) return;

    float* s_all  = ws + OFF_S;
    u32*   eid    = (u32*)(ws + OFF_EID);
    u32*   cnt    = (u32*)(ws + OFF_CNT);
    u32*   offs   = (u32*)(ws + OFF_OFFS);
    float* aggC   = ws + OFF_AGG;
    float* fc_out = ws + OFF_FC;
    float* v      = ws + OFF_V;
    float* epre   = ws + OFF_EPRE;
    float* ent    = ws + OFF_ENT;
    float* relo   = ws + OFF_RELO;
    float* cm     = ws + OFF_CM;
    float* cv     = ws + OFF_CV;
    float* cheq   = ws + OFF_CHEQ;
    float* p0     = ws + OFF_P0;
    float* st0    = ws + OFF_ST0;
    float* chp    = ws + OFF_CHP;
    float* b1sc   = ws + OFF_B1SC;
    float* b1bi   = ws + OFF_B1BI;
    u16*   Wth    = (u16*)(ws + OFF_WTH);
    u16*   Wtl    = (u16*)(ws + OFF_WTL);
    u16*   wT3h   = (u16*)(ws + OFF_WT3H);
    u16*   wT3l   = (u16*)(ws + OFF_WT3L);
    u16*   entH   = (u16*)(ws + OFF_ENTH);
    u16*   entL   = (u16*)(ws + OFF_ENTL);
    u16*   Yh     = (u16*)(ws + OFF_YH);
    u16*   Yl     = (u16*)(ws + OFF_YL);
    __hip_bfloat16* xconv = (__hip_bfloat16*)(ws + OFF_XC);

    // zero counts + agg + fc regions
    hipMemsetAsync(ws + ZERO_BEG, 0, (ZERO_END - ZERO_BEG) * sizeof(float), stream);

    k_vatt<<<2, 256, 0, stream>>>(w_in, w_out, att_in, att_out, v);
    k_wt3<<<(3 * 200 * 224 + 255) / 256, 256, 0, stream>>>(w_in, w_out, w_loop, wT3h, wT3l);

    int edge_wave_blocks = (N_EDGE + 3) / 4;   // 4 waves per 256-thread block
    k_edge_score<<<edge_wave_blocks, 256, 0, stream>>>(init_embed, init_rel, eidx, etype, v, s_all);

    int eb = (N_EDGE + 255) / 256;
    k_hist<<<eb, 256, 0, stream>>>(eidx, cnt);
    k_scan<<<1, 256, 0, stream>>>(cnt, offs);
    k_scatter<<<eb, 256, 0, stream>>>(eidx, cnt, eid);
    k_seg_agg<<<(NSEG + 3) / 4, 256, 0, stream>>>(init_embed, init_rel, eidx, etype,
                                                  s_all, offs, eid, aggC);

    // epre = aggC_in@w_in + aggC_out@w_out + (embed*lr)@w_loop  (MFMA, fused)
    k_epre_mfma<<<(N_ENT + 127) / 128, 256, 0, stream>>>(aggC, init_embed, loop_rel,
                                                         wT3h, wT3l, epre);

    dim3 gR((474 + 63) / 64, (DV + 63) / 64);
    gemm_nn<<<gR, 256, 0, stream>>>(init_rel, w_rel, relo, 474, DV, DV, 0);

    // bn over ent_pre (= 3*ent): /3 folded into eps -> 9*EPS (exact)
    k_colstats<<<DV, 256, 0, stream>>>(epre, N_ENT, cm, cv);
    k_bn_ent<<<((size_t)N_ENT * 208 + 255) / 256, 256, 0, stream>>>(
        epre, cm, cv, bnc_g, bnc_b, ent, entH, entL);

    // Wt split (after edge/gemm regions are dead; before fc)
    dim3 gW(FLATN / 64, 4);
    k_wt<<<gW, 256, 0, stream>>>(fc_w, Wth, Wtl);

    k_cheq<<<BB, 256, 0, stream>>>(ent, relo, sub, rel, perm, cheq, p0);
    k_red_bn0<<<1, 256, 0, stream>>>(p0, st0);
    k_conv<<<BB / 2, 384, 0, stream>>>(cheq, st0, g0, b0, filt, xconv, chp);
    k_bn1_final<<<NF, 256, 0, stream>>>(chp, g1, b1, b1sc, b1bi);

    dim3 gFC(16, 30);
    k_fc_mfma<<<gFC, 256, 0, stream>>>((const u16*)xconv, Wth, Wtl, b1sc, b1bi, fc_out);

    k_colstats<<<DV, 256, 0, stream>>>(fc_out, BB, cm, cv);
    k_bn2y<<<((size_t)BB * 208 + 255) / 256, 256, 0, stream>>>(fc_out, cm, cv, g2, b2, Yh, Yl);

    dim3 gS(16, 57);
    k_sc_mfma<<<gS, 256, 0, stream>>>(Yh, Yl, entH, entL, bias, outp);
}